// Round 14
// baseline (106.895 us; speedup 1.0000x reference)
//
#include <hip/hip_runtime.h>

// Chamfer via MFMA half-distance matrix, v10: INLINE-ASM VGPR-FORCED MFMA.
// R13 post-mortem: 4 structurally different kernels (LDS+barriers, more
// waves, sched_barrier, barrier-free) all = 48.5us, MfmaUtil 27%. Memory
// exonerated (R12 32MB vs R13 512MB L2 traffic, same wall). The tell:
// VGPR_Count=56 < the ~88 minimum for VGPR-resident results => the
// intrinsic's results STILL go to AGPRs; each MFMA pays 16 v_accvgpr_read
// (32cyc VALU). Check: 1024 mfma/SIMD x 32cyc = 13.7us + 6.8us min3 ~= 24us
// = VALUBusy 50% x 48.7 ✓. R9's launch_bounds fix was partial.
// R14: inline asm v_mfma with "=&v" (VGPR class, early-clobber) + 2-deep
// pipeline: issue 4 MFMAs of group B -> sched_barrier(0) -> consume group
// A's 32 min3. Hazard distance (MFMA->VALU read) is >= 4 MFMA issues + 32
// min3 in program order; accvgpr movs eliminated; MFMA pipe and VALU pipe
// overlap intra-wave. Tells: VGPR >= 180 (forced), WRITE ~4-8MB (no spill).
//
// Math (R5-R13 verified, absmax 0.0): h = 0.5|p|^2 + 0.5|t|^2 - p.t = d/2
// via K=16 of v_mfma_f32_32x32x16_bf16 with bf16 hi/lo split:
//   A(p): half0 [xh xh xl yh yh yl zh zh]  half1 [zl ph pl 1 1 0 0 0]
//   B(t): half0 [nxh nxl nxh nyh nyl nyh nzh nzl] half1 [nzh 1 1 hh hl 0 0 0]
// C layout (m74/m101): col=lane&31, row=(reg&3)+8*(reg>>2)+4*(lane>>5).
// Both directions run as row-min MFMA passes (dir1 swaps A/B roles).

typedef float f32x16 __attribute__((ext_vector_type(16)));
typedef short bf16x8 __attribute__((ext_vector_type(8)));

constexpr int BATCH  = 8;
constexpr int NPTS   = 8192;
constexpr int BLOCK  = 256;            // 4 independent waves (no barriers)
constexpr int QTILE  = 256;            // A-points per block (64 per wave)
constexpr int NAF    = 2;              // A-frags per wave
constexpr int QB     = NPTS / QTILE;   // 32 A-blocks per direction
constexpr int DSPLIT = 4;              // db split per direction
constexpr int DBR    = NPTS / DSPLIT;  // 2048 db points per block
constexpr int NT     = DBR / 32;       // 64 B-tiles of 32 points
constexpr int NG     = NT / 2;         // 32 tile-pair groups
constexpr int NBLK   = QB * BATCH * 2 * DSPLIT;   // 2048

// workspace: fragT [B][NPTS][2] uint4 (2MB) | fragS same (2MB)
//            | mins [2][B][NPTS] u32 (512KB)
constexpr size_t FRAG_N = (size_t)BATCH * NPTS * 2;   // uint4s per array
constexpr size_t SM_N   = (size_t)BATCH * NPTS;       // u32 per direction

static __device__ __forceinline__ float fmin3(float a, float b, float c) {
    return fminf(fminf(a, b), c);   // v_min3_f32
}
static __device__ __forceinline__ unsigned short bf16h(float f) {
    unsigned int u = __float_as_uint(f);
    u += 0x7fffu + ((u >> 16) & 1u);           // RNE
    return (unsigned short)(u >> 16);
}
static __device__ __forceinline__ float bf16tof(unsigned short h) {
    return __uint_as_float(((unsigned int)h) << 16);
}
static __device__ __forceinline__ unsigned int pack2(unsigned short a, unsigned short b) {
    return (unsigned int)a | ((unsigned int)b << 16);
}

// VGPR-forced MFMA: "=&v" pins D to the VGPR class (never AGPR) and
// early-clobber keeps D disjoint from A/B/C. volatile preserves relative
// order among the mfmas (pipeline shape).
static __device__ __forceinline__ f32x16 mfma_v(bf16x8 a, bf16x8 b, const f32x16& c) {
    f32x16 d;
    asm volatile("v_mfma_f32_32x32x16_bf16 %0, %1, %2, %3"
                 : "=&v"(d) : "v"(a), "v"(b), "v"(c));
    return d;
}

static __device__ __forceinline__ void make_bfrag(float px, float py, float pz,
                                                  uint4& p0, uint4& p1) {
    const unsigned short one = bf16h(1.0f);
    float nx = -px, ny = -py, nz = -pz;
    float ht = 0.5f * fmaf(px, px, fmaf(py, py, pz * pz));
    unsigned short nxh = bf16h(nx), nxl = bf16h(nx - bf16tof(nxh));
    unsigned short nyh = bf16h(ny), nyl = bf16h(ny - bf16tof(nyh));
    unsigned short nzh = bf16h(nz), nzl = bf16h(nz - bf16tof(nzh));
    unsigned short hh = bf16h(ht),  hl = bf16h(ht - bf16tof(hh));
    p0 = make_uint4(pack2(nxh, nxl), pack2(nxh, nyh),
                    pack2(nyl, nyh), pack2(nzh, nzl));
    p1 = make_uint4(pack2(nzh, one), pack2(one, hh),
                    pack2(hl, 0), 0u);
}

// ---- prep: both arrays -> B-fragments; init mins; zero out ----
__global__ __launch_bounds__(BLOCK) void chamfer_prep(
    const float* __restrict__ src, const float* __restrict__ tgt,
    uint4* __restrict__ fragS, uint4* __restrict__ fragT,
    unsigned int* __restrict__ mins, float* __restrict__ out)
{
    const int i = blockIdx.x * BLOCK + threadIdx.x;   // [0, B*NPTS)
    uint4 p0, p1;
    const float* tp = tgt + (size_t)i * 3;
    make_bfrag(tp[0], tp[1], tp[2], p0, p1);
    fragT[2 * i + 0] = p0;
    fragT[2 * i + 1] = p1;
    const float* sp = src + (size_t)i * 3;
    make_bfrag(sp[0], sp[1], sp[2], p0, p1);
    fragS[2 * i + 0] = p0;
    fragS[2 * i + 1] = p1;
    mins[i]        = 0x7f7f7f7fu;
    mins[SM_N + i] = 0x7f7f7f7fu;
    if (i < BATCH) out[i] = 0.0f;
}

__global__ __launch_bounds__(BLOCK, 2) void chamfer_nn(
    const float* __restrict__ src, const float* __restrict__ tgt,
    const uint4* __restrict__ fragS, const uint4* __restrict__ fragT,
    unsigned int* __restrict__ mins)
{
    const int tid  = threadIdx.x;
    const int lane = tid & 63;
    const int w    = tid >> 6;
    const int half = lane >> 5;
    const int l31  = lane & 31;

    // ---- XCD-panel swizzle (bijective on [0,2048)); validated R10-R13:
    // FETCH 17.3 -> 2.9MB ----
    const int lin  = blockIdx.x;
    const int rest = lin >> 3;                        // [0,256)
    const int qb   = rest & 31;                       // [0,32)
    const int p    = ((rest >> 5) << 3) | (lin & 7);  // panel [0,64)
    const int b    = p & 7;
    const int z    = p >> 3;                          // [0,8)
    const int dir  = z >> 2;   // 0: A=src,B=tgt ; 1: swapped
    const int ds   = z & 3;

    const float* P  = dir ? tgt : src;      // A-side raw points
    const uint4* FB = dir ? fragS : fragT;  // B-side fragments

    // ---- build NAF A-fragments ----
    const unsigned short one = bf16h(1.0f);
    bf16x8 af[NAF];
#pragma unroll
    for (int g = 0; g < NAF; g++) {
        const int q = qb * QTILE + w * (32 * NAF) + g * 32 + l31;
        const float* qp = P + ((size_t)b * NPTS + q) * 3;
        float qx = qp[0], qy = qp[1], qz = qp[2];
        float hq = 0.5f * fmaf(qx, qx, fmaf(qy, qy, qz * qz));
        unsigned short xh = bf16h(qx), xl = bf16h(qx - bf16tof(xh));
        unsigned short yh = bf16h(qy), yl = bf16h(qy - bf16tof(yh));
        unsigned short zh = bf16h(qz), zl = bf16h(qz - bf16tof(zh));
        unsigned short qh = bf16h(hq), ql = bf16h(hq - bf16tof(qh));
        bf16x8 a;
        if (half == 0) {
            a[0] = (short)xh; a[1] = (short)xh; a[2] = (short)xl;
            a[3] = (short)yh; a[4] = (short)yh; a[5] = (short)yl;
            a[6] = (short)zh; a[7] = (short)zh;
        } else {
            a[0] = (short)zl; a[1] = (short)qh; a[2] = (short)ql;
            a[3] = (short)one; a[4] = (short)one;
            a[5] = 0; a[6] = 0; a[7] = 0;
        }
        af[g] = a;
    }

    float rmn0[16], rmn1[16];
#pragma unroll
    for (int r = 0; r < 16; r++) { rmn0[r] = 3.4e38f; rmn1[r] = 3.4e38f; }
    const f32x16 zz = {};   // 16 zero VGPRs, C input for all MFMAs

    // per-lane B pointer (element 64*t + 2*l31 + half); coalesced 1KB/tile,
    // L2-resident by swizzle. No LDS, no barriers.
    const uint4* gp = FB + ((size_t)b * NPTS + (size_t)ds * DBR) * 2
                         + 2 * l31 + half;

    // ---- 2-deep pipelined pair-groups: issue B, consume A, flip ----
    uint4 c0 = gp[0], c1 = gp[64];
    f32x16 dA00, dA01, dA10, dA11;
    {   // prologue: issue group 0 (A)
        bf16x8 b0 = __builtin_bit_cast(bf16x8, c0);
        bf16x8 b1 = __builtin_bit_cast(bf16x8, c1);
        c0 = gp[128]; c1 = gp[192];          // group 1 data
        dA00 = mfma_v(af[0], b0, zz); dA01 = mfma_v(af[0], b1, zz);
        dA10 = mfma_v(af[1], b0, zz); dA11 = mfma_v(af[1], b1, zz);
    }
    for (int g = 1; g <= NG - 3; g += 2) {   // g = 1,3,...,29
        // issue group g (B); prefetch g+1
        bf16x8 b0 = __builtin_bit_cast(bf16x8, c0);
        bf16x8 b1 = __builtin_bit_cast(bf16x8, c1);
        c0 = gp[128 * (g + 1)]; c1 = gp[128 * (g + 1) + 64];
        f32x16 dB00 = mfma_v(af[0], b0, zz), dB01 = mfma_v(af[0], b1, zz);
        f32x16 dB10 = mfma_v(af[1], b0, zz), dB11 = mfma_v(af[1], b1, zz);
        __builtin_amdgcn_sched_barrier(0);
        // consume group g-1 (A) while B grinds the matrix pipe
#pragma unroll
        for (int r = 0; r < 16; r++) {
            rmn0[r] = fmin3(rmn0[r], dA00[r], dA01[r]);
            rmn1[r] = fmin3(rmn1[r], dA10[r], dA11[r]);
        }
        // issue group g+1 (A); prefetch g+2
        b0 = __builtin_bit_cast(bf16x8, c0);
        b1 = __builtin_bit_cast(bf16x8, c1);
        c0 = gp[128 * (g + 2)]; c1 = gp[128 * (g + 2) + 64];
        dA00 = mfma_v(af[0], b0, zz); dA01 = mfma_v(af[0], b1, zz);
        dA10 = mfma_v(af[1], b0, zz); dA11 = mfma_v(af[1], b1, zz);
        __builtin_amdgcn_sched_barrier(0);
        // consume group g (B)
#pragma unroll
        for (int r = 0; r < 16; r++) {
            rmn0[r] = fmin3(rmn0[r], dB00[r], dB01[r]);
            rmn1[r] = fmin3(rmn1[r], dB10[r], dB11[r]);
        }
    }
    {   // tail: issue group 31 (B), consume 30 (A), consume 31 (B)
        bf16x8 b0 = __builtin_bit_cast(bf16x8, c0);
        bf16x8 b1 = __builtin_bit_cast(bf16x8, c1);
        f32x16 dB00 = mfma_v(af[0], b0, zz), dB01 = mfma_v(af[0], b1, zz);
        f32x16 dB10 = mfma_v(af[1], b0, zz), dB11 = mfma_v(af[1], b1, zz);
        __builtin_amdgcn_sched_barrier(0);
#pragma unroll
        for (int r = 0; r < 16; r++) {
            rmn0[r] = fmin3(rmn0[r], dA00[r], dA01[r]);
            rmn1[r] = fmin3(rmn1[r], dA10[r], dA11[r]);
        }
#pragma unroll
        for (int r = 0; r < 16; r++) {
            rmn0[r] = fmin3(rmn0[r], dB00[r], dB01[r]);
            rmn1[r] = fmin3(rmn1[r], dB10[r], dB11[r]);
        }
    }

    // ---- epilogue: fold cols 32->1 in-wave, global atomicMin merge ----
    unsigned int* M = mins + ((size_t)dir * BATCH + b) * NPTS;
    const int qbase = qb * QTILE + w * (32 * NAF);
#pragma unroll
    for (int r = 0; r < 16; r++) {
        float a = rmn0[r], bv = rmn1[r];
#pragma unroll
        for (int off = 16; off > 0; off >>= 1) {
            a  = fminf(a,  __shfl_xor(a,  off, 64));
            bv = fminf(bv, __shfl_xor(bv, off, 64));
        }
        if (l31 == 0) {   // lanes 0 (half0 row) and 32 (half1 row)
            const int row = (r & 3) + 8 * (r >> 2) + 4 * half;
            atomicMin(&M[qbase + row],      __float_as_uint(fmaxf(a,  0.0f)));
            atomicMin(&M[qbase + 32 + row], __float_as_uint(fmaxf(bv, 0.0f)));
        }
    }
}

// ---- final: sum mins[2][B][NPTS] (512KB), atomicAdd into out ----
__global__ __launch_bounds__(BLOCK) void chamfer_final(
    const unsigned int* __restrict__ mins, float* __restrict__ out)
{
    const int seg = blockIdx.x;   // 4 segments of 2048
    const int b   = blockIdx.y;
    const int tid = threadIdx.x;
    float acc = 0.0f;
#pragma unroll
    for (int k = 0; k < 8; k++) {
        const size_t i = (size_t)b * NPTS + seg * 2048 + k * BLOCK + tid;
        acc += __uint_as_float(mins[i]) + __uint_as_float(mins[SM_N + i]);
    }
    for (int off = 32; off > 0; off >>= 1) acc += __shfl_down(acc, off, 64);
    __shared__ float wsum[4];
    if ((tid & 63) == 0) wsum[tid >> 6] = acc;
    __syncthreads();
    if (tid == 0)   // stored values are half-distances: d = 2h
        atomicAdd(&out[b],
                  (wsum[0] + wsum[1] + wsum[2] + wsum[3]) * (2.0f / (float)NPTS));
}

extern "C" void kernel_launch(void* const* d_in, const int* in_sizes, int n_in,
                              void* d_out, int out_size, void* d_ws, size_t ws_size,
                              hipStream_t stream) {
    const float* src = (const float*)d_in[0];  // [B, N, 3]
    const float* tgt = (const float*)d_in[1];  // [B, M, 3]
    float* out = (float*)d_out;                // [B]

    uint4* fragT        = (uint4*)d_ws;                     // 2 MB
    uint4* fragS        = fragT + FRAG_N;                   // 2 MB
    unsigned int* mins  = (unsigned int*)(fragS + FRAG_N);  // 512 KB

    chamfer_prep<<<BATCH * NPTS / BLOCK, BLOCK, 0, stream>>>(
        src, tgt, fragS, fragT, mins, out);
    chamfer_nn<<<NBLK, BLOCK, 0, stream>>>(
        src, tgt, fragS, fragT, mins);
    chamfer_final<<<dim3(4, BATCH), BLOCK, 0, stream>>>(mins, out);
}

// Round 16
// 100.157 us; speedup vs baseline: 1.0673x; 1.0673x over previous
//
#include <hip/hip_runtime.h>

// Chamfer via MFMA half-distance matrix, v12: UNSIGNED-INT MIN DOMAIN.
// R15 post-mortem: inline-asm v_min3 reading intrinsic MFMA results broke
// correctness (absmax 7.6e-3) -- the MAI hazard recognizer inserts MFMA->
// VALU wait states for compiler-generated consumers but not for opaque
// INLINEASM reads (read ~8cyc after issue < ~32cyc write latency = stale
// regs). Matrix: intrinsic+fminf OK/slow, asm-MFMA+fminf OK/slow,
// intrinsic+asm-min BROKEN. Canonicalize theory (fminf = ~3 inst due to
// sNaN quieting, = the invariant ~24us/SIMD VALU) still live, untimed.
// R16: single-inst min WITHOUT asm: burn k-slot 13 (A=1, B=1) so the MFMA
// emits h+1 (>= 0.99, strictly positive); positive IEEE floats order as
// their u32 bit patterns, so row-min = v_min3_u32 via plain C ternaries
// (no canonicalize ever on int ops; compiler-scheduled => hazard-safe).
// Merge chain stays in u32; final kernel un-biases (-1.0) and clamps.
// Bias rounding ~2e-6 vs threshold 9.5e-4. Structure = R13 (proven 48.5us:
// barrier-free, LDS-free, XCD-swizzled, reg-prefetch).
//
// Math: h = 0.5|p|^2 + 0.5|t|^2 - p.t = d/2 via K=16 mfma_f32_32x32x16_bf16,
// bf16 hi/lo split; now with +1 bias slot:
//   A(p): half0 [xh xh xl yh yh yl zh zh]  half1 [zl ph pl 1 1 1 0 0]
//   B(t): half0 [nxh nxl nxh nyh nyl nyh nzh nzl] half1 [nzh 1 1 hh hl 1 0 0]
// C layout (m74/m101): col=lane&31, row=(reg&3)+8*(reg>>2)+4*(lane>>5).
// Both directions run as row-min MFMA passes (dir1 swaps A/B roles).

typedef float f32x16 __attribute__((ext_vector_type(16)));
typedef short bf16x8 __attribute__((ext_vector_type(8)));

constexpr int BATCH  = 8;
constexpr int NPTS   = 8192;
constexpr int BLOCK  = 256;            // 4 independent waves (no barriers)
constexpr int QTILE  = 256;            // A-points per block (64 per wave)
constexpr int NAF    = 2;              // A-frags per wave
constexpr int QB     = NPTS / QTILE;   // 32 A-blocks per direction
constexpr int DSPLIT = 4;              // db split per direction
constexpr int DBR    = NPTS / DSPLIT;  // 2048 db points per block
constexpr int NT     = DBR / 32;       // 64 B-tiles of 32 points
constexpr int NBLK   = QB * BATCH * 2 * DSPLIT;   // 2048

// workspace: fragT [B][NPTS][2] uint4 (2MB) | fragS same (2MB)
//            | mins [2][B][NPTS] u32 (512KB)
constexpr size_t FRAG_N = (size_t)BATCH * NPTS * 2;   // uint4s per array
constexpr size_t SM_N   = (size_t)BATCH * NPTS;       // u32 per direction

static __device__ __forceinline__ unsigned umin2(unsigned a, unsigned b) {
    return a < b ? a : b;               // v_min_u32
}
static __device__ __forceinline__ unsigned umin3(unsigned a, unsigned b, unsigned c) {
    return umin2(a, umin2(b, c));       // fuses to v_min3_u32
}
static __device__ __forceinline__ unsigned short bf16h(float f) {
    unsigned int u = __float_as_uint(f);
    u += 0x7fffu + ((u >> 16) & 1u);           // RNE
    return (unsigned short)(u >> 16);
}
static __device__ __forceinline__ float bf16tof(unsigned short h) {
    return __uint_as_float(((unsigned int)h) << 16);
}
static __device__ __forceinline__ unsigned int pack2(unsigned short a, unsigned short b) {
    return (unsigned int)a | ((unsigned int)b << 16);
}

static __device__ __forceinline__ void make_bfrag(float px, float py, float pz,
                                                  uint4& p0, uint4& p1) {
    const unsigned short one = bf16h(1.0f);
    float nx = -px, ny = -py, nz = -pz;
    float ht = 0.5f * fmaf(px, px, fmaf(py, py, pz * pz));
    unsigned short nxh = bf16h(nx), nxl = bf16h(nx - bf16tof(nxh));
    unsigned short nyh = bf16h(ny), nyl = bf16h(ny - bf16tof(nyh));
    unsigned short nzh = bf16h(nz), nzl = bf16h(nz - bf16tof(nzh));
    unsigned short hh = bf16h(ht),  hl = bf16h(ht - bf16tof(hh));
    p0 = make_uint4(pack2(nxh, nxl), pack2(nxh, nyh),
                    pack2(nyl, nyh), pack2(nzh, nzl));
    p1 = make_uint4(pack2(nzh, one), pack2(one, hh),
                    pack2(hl, one), 0u);    // slot 13 = 1 (bias: pairs A's 1)
}

// ---- prep: both arrays -> B-fragments; init mins; zero out ----
__global__ __launch_bounds__(BLOCK) void chamfer_prep(
    const float* __restrict__ src, const float* __restrict__ tgt,
    uint4* __restrict__ fragS, uint4* __restrict__ fragT,
    unsigned int* __restrict__ mins, float* __restrict__ out)
{
    const int i = blockIdx.x * BLOCK + threadIdx.x;   // [0, B*NPTS)
    uint4 p0, p1;
    const float* tp = tgt + (size_t)i * 3;
    make_bfrag(tp[0], tp[1], tp[2], p0, p1);
    fragT[2 * i + 0] = p0;
    fragT[2 * i + 1] = p1;
    const float* sp = src + (size_t)i * 3;
    make_bfrag(sp[0], sp[1], sp[2], p0, p1);
    fragS[2 * i + 0] = p0;
    fragS[2 * i + 1] = p1;
    mins[i]        = 0x7f7f7f7fu;   // huge positive float bits
    mins[SM_N + i] = 0x7f7f7f7fu;
    if (i < BATCH) out[i] = 0.0f;
}

__global__ __launch_bounds__(BLOCK, 2) void chamfer_nn(
    const float* __restrict__ src, const float* __restrict__ tgt,
    const uint4* __restrict__ fragS, const uint4* __restrict__ fragT,
    unsigned int* __restrict__ mins)
{
    const int tid  = threadIdx.x;
    const int lane = tid & 63;
    const int w    = tid >> 6;
    const int half = lane >> 5;
    const int l31  = lane & 31;

    // ---- XCD-panel swizzle (bijective on [0,2048)); validated R10-R14:
    // FETCH 17.3 -> 2.9MB ----
    const int lin  = blockIdx.x;
    const int rest = lin >> 3;                        // [0,256)
    const int qb   = rest & 31;                       // [0,32)
    const int p    = ((rest >> 5) << 3) | (lin & 7);  // panel [0,64)
    const int b    = p & 7;
    const int z    = p >> 3;                          // [0,8)
    const int dir  = z >> 2;   // 0: A=src,B=tgt ; 1: swapped
    const int ds   = z & 3;

    const float* P  = dir ? tgt : src;      // A-side raw points
    const uint4* FB = dir ? fragS : fragT;  // B-side fragments

    // ---- build NAF A-fragments ----
    const unsigned short one = bf16h(1.0f);
    bf16x8 af[NAF];
#pragma unroll
    for (int g = 0; g < NAF; g++) {
        const int q = qb * QTILE + w * (32 * NAF) + g * 32 + l31;
        const float* qp = P + ((size_t)b * NPTS + q) * 3;
        float qx = qp[0], qy = qp[1], qz = qp[2];
        float hq = 0.5f * fmaf(qx, qx, fmaf(qy, qy, qz * qz));
        unsigned short xh = bf16h(qx), xl = bf16h(qx - bf16tof(xh));
        unsigned short yh = bf16h(qy), yl = bf16h(qy - bf16tof(yh));
        unsigned short zh = bf16h(qz), zl = bf16h(qz - bf16tof(zh));
        unsigned short qh = bf16h(hq), ql = bf16h(hq - bf16tof(qh));
        bf16x8 a;
        if (half == 0) {
            a[0] = (short)xh; a[1] = (short)xh; a[2] = (short)xl;
            a[3] = (short)yh; a[4] = (short)yh; a[5] = (short)yl;
            a[6] = (short)zh; a[7] = (short)zh;
        } else {
            a[0] = (short)zl; a[1] = (short)qh; a[2] = (short)ql;
            a[3] = (short)one; a[4] = (short)one;
            a[5] = (short)one;  // slot 13: pairs B's 1 -> +1.0 bias
            a[6] = 0; a[7] = 0;
        }
        af[g] = a;
    }

    unsigned rmn0[16], rmn1[16];
#pragma unroll
    for (int r = 0; r < 16; r++) { rmn0[r] = 0x7f7f7f7fu; rmn1[r] = 0x7f7f7f7fu; }
    const f32x16 zz = {};   // zero C input for all MFMAs

    // per-lane B pointer (element 64*t + 2*l31 + half); coalesced 1KB/tile,
    // L2-resident by swizzle. No LDS, no barriers: waves free-run.
    const uint4* gp = FB + ((size_t)b * NPTS + (size_t)ds * DBR) * 2
                         + 2 * l31 + half;

    // register prefetch, 1-iteration distance (T14)
    uint4 c0 = gp[0], c1 = gp[64];
    for (int t = 0; t < NT; t += 2) {
        bf16x8 b0 = __builtin_bit_cast(bf16x8, c0);
        bf16x8 b1 = __builtin_bit_cast(bf16x8, c1);
        if (t + 2 < NT) {                   // issue next pair early
            c0 = gp[64 * (t + 2)];
            c1 = gp[64 * (t + 3)];
        }
        f32x16 a00 = __builtin_amdgcn_mfma_f32_32x32x16_bf16(af[0], b0, zz, 0, 0, 0);
        f32x16 a01 = __builtin_amdgcn_mfma_f32_32x32x16_bf16(af[0], b1, zz, 0, 0, 0);
        f32x16 a10 = __builtin_amdgcn_mfma_f32_32x32x16_bf16(af[1], b0, zz, 0, 0, 0);
        f32x16 a11 = __builtin_amdgcn_mfma_f32_32x32x16_bf16(af[1], b1, zz, 0, 0, 0);
        // results are h+1 > 0: u32 bit order == float order -> v_min3_u32
#pragma unroll
        for (int r = 0; r < 16; r++) {
            rmn0[r] = umin3(rmn0[r], __float_as_uint(a00[r]), __float_as_uint(a01[r]));
            rmn1[r] = umin3(rmn1[r], __float_as_uint(a10[r]), __float_as_uint(a11[r]));
        }
    }

    // ---- epilogue: fold cols 32->1 in-wave (u32), global atomicMin ----
    unsigned int* M = mins + ((size_t)dir * BATCH + b) * NPTS;
    const int qbase = qb * QTILE + w * (32 * NAF);
#pragma unroll
    for (int r = 0; r < 16; r++) {
        unsigned a = rmn0[r], bv = rmn1[r];
#pragma unroll
        for (int off = 16; off > 0; off >>= 1) {
            a  = umin2(a,  (unsigned)__shfl_xor((int)a,  off, 64));
            bv = umin2(bv, (unsigned)__shfl_xor((int)bv, off, 64));
        }
        if (l31 == 0) {   // lanes 0 (half0 row) and 32 (half1 row)
            const int row = (r & 3) + 8 * (r >> 2) + 4 * half;
            atomicMin(&M[qbase + row],      a);
            atomicMin(&M[qbase + 32 + row], bv);
        }
    }
}

// ---- final: un-bias, clamp, sum mins[2][B][NPTS], atomicAdd into out ----
__global__ __launch_bounds__(BLOCK) void chamfer_final(
    const unsigned int* __restrict__ mins, float* __restrict__ out)
{
    const int seg = blockIdx.x;   // 4 segments of 2048
    const int b   = blockIdx.y;
    const int tid = threadIdx.x;
    float acc = 0.0f;
#pragma unroll
    for (int k = 0; k < 8; k++) {
        const size_t i = (size_t)b * NPTS + seg * 2048 + k * BLOCK + tid;
        acc += fmaxf(__uint_as_float(mins[i]) - 1.0f, 0.0f)
             + fmaxf(__uint_as_float(mins[SM_N + i]) - 1.0f, 0.0f);
    }
    for (int off = 32; off > 0; off >>= 1) acc += __shfl_down(acc, off, 64);
    __shared__ float wsum[4];
    if ((tid & 63) == 0) wsum[tid >> 6] = acc;
    __syncthreads();
    if (tid == 0)   // stored values are (d/2 + 1): d = 2*(v-1)
        atomicAdd(&out[b],
                  (wsum[0] + wsum[1] + wsum[2] + wsum[3]) * (2.0f / (float)NPTS));
}

extern "C" void kernel_launch(void* const* d_in, const int* in_sizes, int n_in,
                              void* d_out, int out_size, void* d_ws, size_t ws_size,
                              hipStream_t stream) {
    const float* src = (const float*)d_in[0];  // [B, N, 3]
    const float* tgt = (const float*)d_in[1];  // [B, M, 3]
    float* out = (float*)d_out;                // [B]

    uint4* fragT        = (uint4*)d_ws;                     // 2 MB
    uint4* fragS        = fragT + FRAG_N;                   // 2 MB
    unsigned int* mins  = (unsigned int*)(fragS + FRAG_N);  // 512 KB

    chamfer_prep<<<BATCH * NPTS / BLOCK, BLOCK, 0, stream>>>(
        src, tgt, fragS, fragT, mins, out);
    chamfer_nn<<<NBLK, BLOCK, 0, stream>>>(
        src, tgt, fragS, fragT, mins);
    chamfer_final<<<dim3(4, BATCH), BLOCK, 0, stream>>>(mins, out);
}

// Round 17
// 96.949 us; speedup vs baseline: 1.1026x; 1.0331x over previous
//
#include <hip/hip_runtime.h>

// Chamfer via MFMA half-distance matrix, v13: SINGLE-PASS (u32 min domain).
// R16 post-mortem: u32-min correct but only -2.3us -- canonicalize was NOT
// the 24us. The closing model: MfmaUtil+VALUBusy ~= 72% in EVERY round
// R9-R16 -- the two pipes are ADDITIVE, not overlapped. Wall ~= (MFMA 13.7
// + VALU ~20) x 1.35 = 46us. Structures never changed the demand sum.
// R17 halves the MFMA term: the dir-1 pass was pure redundancy (recompute
// every h for row-major t2s). With u32 min3 (cheap, hazard-safe, validated
// R16), the per-tile col-min tree costs 17 ops -> single pass computes each
// unique tile ONCE: s2t row-accumulate in regs (as before), t2s via u32
// tree16 + shfl_xor(32) + LDS ds_min_u32 into block-shared sht[2048]
// (atomics need no barrier; 2 barriers total), one global flush per block.
// B-load traffic and prep also halve. mins bitwise identical (min is
// order-independent) -> absmax 0.0.
//
// Math (R5-R16 verified): h+1 = 0.5|p|^2 + 0.5|t|^2 - p.t + 1 via K=16
// mfma_f32_32x32x16_bf16, bf16 hi/lo split, bias slot 13 (A=1,B=1):
//   A(q): half0 [xh xh xl yh yh yl zh zh]  half1 [zl qh ql 1 1 1 0 0]
//   B(t): half0 [nxh nxl nxh nyh nyl nyh nzh nzl] half1 [nzh 1 1 hh hl 1 0 0]
// h+1 >= 0.99 > 0, so u32 bit order == float order (R16-validated).
// C layout (m74/m101): col=lane&31 (db pt), row=(reg&3)+8*(reg>>2)+4*half.

typedef float f32x16 __attribute__((ext_vector_type(16)));
typedef short bf16x8 __attribute__((ext_vector_type(8)));

constexpr int BATCH  = 8;
constexpr int NPTS   = 8192;
constexpr int BLOCK  = 256;            // 4 waves
constexpr int QTILE  = 256;            // queries per block (64 per wave)
constexpr int NAF    = 2;              // A-frags per wave
constexpr int QB     = NPTS / QTILE;   // 32 query blocks
constexpr int DSPLIT = 4;              // db split
constexpr int DBR    = NPTS / DSPLIT;  // 2048 db points per block
constexpr int NT     = DBR / 32;       // 64 B-tiles of 32 points
constexpr int NBLK   = QB * BATCH * DSPLIT;   // 1024 (single pass!)

// workspace: fragT [B][NPTS][2] uint4 (2MB) | mins [2][B][NPTS] u32 (512KB)
constexpr size_t FRAG_N = (size_t)BATCH * NPTS * 2;   // uint4s
constexpr size_t SM_N   = (size_t)BATCH * NPTS;       // u32 per direction

static __device__ __forceinline__ unsigned umin2(unsigned a, unsigned b) {
    return a < b ? a : b;               // v_min_u32
}
static __device__ __forceinline__ unsigned umin3(unsigned a, unsigned b, unsigned c) {
    return umin2(a, umin2(b, c));       // fuses to v_min3_u32
}
static __device__ __forceinline__ unsigned u(float f) { return __float_as_uint(f); }

// min over the 16 fp32 lanes-regs of one MFMA result, in u32 domain (8 ops)
static __device__ __forceinline__ unsigned tree16u(const f32x16& a) {
    unsigned m = umin3(u(a[0]), u(a[1]), u(a[2]));
    m = umin3(m, u(a[3]),  u(a[4]));  m = umin3(m, u(a[5]),  u(a[6]));
    m = umin3(m, u(a[7]),  u(a[8]));  m = umin3(m, u(a[9]),  u(a[10]));
    m = umin3(m, u(a[11]), u(a[12])); m = umin3(m, u(a[13]), u(a[14]));
    return umin2(m, u(a[15]));
}

static __device__ __forceinline__ unsigned short bf16h(float f) {
    unsigned int v = __float_as_uint(f);
    v += 0x7fffu + ((v >> 16) & 1u);           // RNE
    return (unsigned short)(v >> 16);
}
static __device__ __forceinline__ float bf16tof(unsigned short h) {
    return __uint_as_float(((unsigned int)h) << 16);
}
static __device__ __forceinline__ unsigned int pack2(unsigned short a, unsigned short b) {
    return (unsigned int)a | ((unsigned int)b << 16);
}

// ---- prep: tgt -> B-fragments; init mins; zero out ----
__global__ __launch_bounds__(BLOCK) void chamfer_prep(
    const float* __restrict__ tgt, uint4* __restrict__ fragT,
    unsigned int* __restrict__ mins, float* __restrict__ out)
{
    const int i = blockIdx.x * BLOCK + threadIdx.x;   // [0, B*NPTS)
    const unsigned short one = bf16h(1.0f);
    const float* tp = tgt + (size_t)i * 3;
    float px = tp[0], py = tp[1], pz = tp[2];
    float nx = -px, ny = -py, nz = -pz;
    float ht = 0.5f * fmaf(px, px, fmaf(py, py, pz * pz));
    unsigned short nxh = bf16h(nx), nxl = bf16h(nx - bf16tof(nxh));
    unsigned short nyh = bf16h(ny), nyl = bf16h(ny - bf16tof(nyh));
    unsigned short nzh = bf16h(nz), nzl = bf16h(nz - bf16tof(nzh));
    unsigned short hh = bf16h(ht),  hl = bf16h(ht - bf16tof(hh));
    fragT[2 * i + 0] = make_uint4(pack2(nxh, nxl), pack2(nxh, nyh),
                                  pack2(nyl, nyh), pack2(nzh, nzl));
    fragT[2 * i + 1] = make_uint4(pack2(nzh, one), pack2(one, hh),
                                  pack2(hl, one), 0u);   // slot 13 = 1 (bias)
    mins[i]        = 0x7f7f7f7fu;
    mins[SM_N + i] = 0x7f7f7f7fu;
    if (i < BATCH) out[i] = 0.0f;
}

__global__ __launch_bounds__(BLOCK, 2) void chamfer_nn(
    const float* __restrict__ src, const uint4* __restrict__ fragT,
    unsigned int* __restrict__ mins)
{
    __shared__ unsigned sht[DBR];   // per-db-point col-min (biased u32), 8KB

    const int tid  = threadIdx.x;
    const int lane = tid & 63;
    const int w    = tid >> 6;
    const int half = lane >> 5;
    const int l31  = lane & 31;

    // ---- XCD-panel swizzle (bijective on [0,1024)) ----
    // panel = (b,ds) in [0,32); its 32 qb-siblings share lin&7 -> same XCD
    // -> 64KB fragment panel L2-resident (validated R10-R16: FETCH ~2.9MB).
    const int lin  = blockIdx.x;
    const int rest = lin >> 3;                        // [0,128)
    const int qb   = rest & 31;                       // [0,32)
    const int p    = ((rest >> 5) << 3) | (lin & 7);  // panel [0,32)
    const int b    = p & 7;
    const int ds   = p >> 3;                          // [0,4)

    // init col-min slots, then one barrier before any wave's ds_min
    for (int j = tid; j < DBR; j += BLOCK) sht[j] = 0x7f7f7f7fu;

    // ---- build NAF A-fragments from src ----
    const unsigned short one = bf16h(1.0f);
    bf16x8 af[NAF];
#pragma unroll
    for (int g = 0; g < NAF; g++) {
        const int q = qb * QTILE + w * (32 * NAF) + g * 32 + l31;
        const float* qp = src + ((size_t)b * NPTS + q) * 3;
        float qx = qp[0], qy = qp[1], qz = qp[2];
        float hq = 0.5f * fmaf(qx, qx, fmaf(qy, qy, qz * qz));
        unsigned short xh = bf16h(qx), xl = bf16h(qx - bf16tof(xh));
        unsigned short yh = bf16h(qy), yl = bf16h(qy - bf16tof(yh));
        unsigned short zh = bf16h(qz), zl = bf16h(qz - bf16tof(zh));
        unsigned short qh = bf16h(hq), ql = bf16h(hq - bf16tof(qh));
        bf16x8 a;
        if (half == 0) {
            a[0] = (short)xh; a[1] = (short)xh; a[2] = (short)xl;
            a[3] = (short)yh; a[4] = (short)yh; a[5] = (short)yl;
            a[6] = (short)zh; a[7] = (short)zh;
        } else {
            a[0] = (short)zl; a[1] = (short)qh; a[2] = (short)ql;
            a[3] = (short)one; a[4] = (short)one;
            a[5] = (short)one;  // slot 13: pairs B's 1 -> +1.0 bias
            a[6] = 0; a[7] = 0;
        }
        af[g] = a;
    }

    unsigned rmn0[16], rmn1[16];
#pragma unroll
    for (int r = 0; r < 16; r++) { rmn0[r] = 0x7f7f7f7fu; rmn1[r] = 0x7f7f7f7fu; }
    const f32x16 zz = {};

    // per-lane B pointer (element 64*t + 2*l31 + half); coalesced, L2-hot.
    const uint4* gp = fragT + ((size_t)b * NPTS + (size_t)ds * DBR) * 2
                            + 2 * l31 + half;

    __syncthreads();   // sht init visible before any ds_min

    // register prefetch, 1-iteration distance (T14)
    uint4 c0 = gp[0], c1 = gp[64];
    for (int t = 0; t < NT; t += 2) {
        bf16x8 b0 = __builtin_bit_cast(bf16x8, c0);
        bf16x8 b1 = __builtin_bit_cast(bf16x8, c1);
        if (t + 2 < NT) {                   // issue next pair early
            c0 = gp[64 * (t + 2)];
            c1 = gp[64 * (t + 3)];
        }
        // ONE MFMA per unique tile x A-group (no dir-1 pass)
        f32x16 a00 = __builtin_amdgcn_mfma_f32_32x32x16_bf16(af[0], b0, zz, 0, 0, 0);
        f32x16 a01 = __builtin_amdgcn_mfma_f32_32x32x16_bf16(af[0], b1, zz, 0, 0, 0);
        f32x16 a10 = __builtin_amdgcn_mfma_f32_32x32x16_bf16(af[1], b0, zz, 0, 0, 0);
        f32x16 a11 = __builtin_amdgcn_mfma_f32_32x32x16_bf16(af[1], b1, zz, 0, 0, 0);
        // s2t: row-min accumulate (min over db points), u32 domain
#pragma unroll
        for (int r = 0; r < 16; r++) {
            rmn0[r] = umin3(rmn0[r], u(a00[r]), u(a01[r]));
            rmn1[r] = umin3(rmn1[r], u(a10[r]), u(a11[r]));
        }
        // t2s: col-min per tile over this wave's 64 queries
        unsigned t0 = umin2(tree16u(a00), tree16u(a10));   // tile t
        unsigned t1 = umin2(tree16u(a01), tree16u(a11));   // tile t+1
        t0 = umin2(t0, (unsigned)__shfl_xor((int)t0, 32, 64));
        t1 = umin2(t1, (unsigned)__shfl_xor((int)t1, 32, 64));
        if (half == 0) {   // 32 lanes -> 32 distinct 4B slots (bank-clean)
            atomicMin(&sht[t * 32 + l31],       t0);
            atomicMin(&sht[(t + 1) * 32 + l31], t1);
        }
    }

    // ---- s2t epilogue: fold cols 32->1 in-wave, global atomicMin ----
    unsigned int* M0 = mins + (size_t)b * NPTS;
    const int qbase = qb * QTILE + w * (32 * NAF);
#pragma unroll
    for (int r = 0; r < 16; r++) {
        unsigned a = rmn0[r], bv = rmn1[r];
#pragma unroll
        for (int off = 16; off > 0; off >>= 1) {
            a  = umin2(a,  (unsigned)__shfl_xor((int)a,  off, 64));
            bv = umin2(bv, (unsigned)__shfl_xor((int)bv, off, 64));
        }
        if (l31 == 0) {   // lanes 0 (half0 row) and 32 (half1 row)
            const int row = (r & 3) + 8 * (r >> 2) + 4 * half;
            atomicMin(&M0[qbase + row],      a);
            atomicMin(&M0[qbase + 32 + row], bv);
        }
    }

    // ---- t2s epilogue: one global flush of the block's col-mins ----
    __syncthreads();   // all waves' ds_min complete
    unsigned int* M1 = mins + SM_N + (size_t)b * NPTS + (size_t)ds * DBR;
    for (int j = tid; j < DBR; j += BLOCK)
        atomicMin(&M1[j], sht[j]);
}

// ---- final: un-bias, clamp, sum mins[2][B][NPTS], atomicAdd into out ----
__global__ __launch_bounds__(BLOCK) void chamfer_final(
    const unsigned int* __restrict__ mins, float* __restrict__ out)
{
    const int seg = blockIdx.x;   // 4 segments of 2048
    const int b   = blockIdx.y;
    const int tid = threadIdx.x;
    float acc = 0.0f;
#pragma unroll
    for (int k = 0; k < 8; k++) {
        const size_t i = (size_t)b * NPTS + seg * 2048 + k * BLOCK + tid;
        acc += fmaxf(__uint_as_float(mins[i]) - 1.0f, 0.0f)
             + fmaxf(__uint_as_float(mins[SM_N + i]) - 1.0f, 0.0f);
    }
    for (int off = 32; off > 0; off >>= 1) acc += __shfl_down(acc, off, 64);
    __shared__ float wsum[4];
    if ((tid & 63) == 0) wsum[tid >> 6] = acc;
    __syncthreads();
    if (tid == 0)   // stored values are (d/2 + 1): d = 2*(v-1)
        atomicAdd(&out[b],
                  (wsum[0] + wsum[1] + wsum[2] + wsum[3]) * (2.0f / (float)NPTS));
}

extern "C" void kernel_launch(void* const* d_in, const int* in_sizes, int n_in,
                              void* d_out, int out_size, void* d_ws, size_t ws_size,
                              hipStream_t stream) {
    const float* src = (const float*)d_in[0];  // [B, N, 3]
    const float* tgt = (const float*)d_in[1];  // [B, M, 3]
    float* out = (float*)d_out;                // [B]

    uint4* fragT        = (uint4*)d_ws;                     // 2 MB
    unsigned int* mins  = (unsigned int*)(fragT + FRAG_N);  // 512 KB

    chamfer_prep<<<BATCH * NPTS / BLOCK, BLOCK, 0, stream>>>(
        tgt, fragT, mins, out);
    chamfer_nn<<<NBLK, BLOCK, 0, stream>>>(src, fragT, mins);
    chamfer_final<<<dim3(4, BATCH), BLOCK, 0, stream>>>(mins, out);
}